// Round 3
// baseline (19443.938 us; speedup 1.0000x reference)
//
#include <hip/hip_runtime.h>

// 2-layer LSTM, B=64, S=2048, F=40, EMB=128, HID=256 — R3 "NJ=2 + helper" design.
// Per group (16 batches):
//   role0: 2 chainL0 blocks (512thr), each: W_hh0 half (128 VGPR/thr) + folded
//          input proj W_comb half; exchange h0 halves via tagged-u64 IF$ ring.
//   role1: 2 helper blocks: W_ih1 half; consume h0 ring, publish bias-folded
//          ix1 preacts (pk hi/lo) into deep ring (off critical path).
//   role2: 2 chainL1 blocks: W_hh1 half; partner h1 half + ix1 ring; gates
//          combined wave-locally (shfl_xor 8); out-proj partials -> ghout ->
//          post reduce kernel. No atomics, no fences; relaxed tagged u64 only.

#define Sz 2048

typedef __attribute__((ext_vector_type(8))) short short8;
typedef __attribute__((ext_vector_type(4))) float f32x4;

// ws layout: u64 units for rings
#define H1_BASE 131072            // after H0: 4*8*2*2048
#define IX_BASE 196608            // after H1: +4*4*2*2048
// u32 units
#define CF_WORD 1441792           // mdcf[8], c1cf[8] at +8
#define GH_WORD 1441824           // [g][2][Sz][16] f32
#define ZERO_WORDS 1441824

// LDS byte offsets
#define HA_HI 0
#define HA_LO 8448
#define IN_HI 16896               // role0: 16 x 144B x2 planes
#define IN_LO 19200
#define POUT_LDS 16896            // role2 alias: 2*128 floats
#define SMEM_BYTES 21504

__device__ __forceinline__ unsigned short bf16_rne(float f) {
  unsigned u = __float_as_uint(f);
  u += 0x7FFFu + ((u >> 16) & 1u);
  return (unsigned short)(u >> 16);
}
__device__ __forceinline__ unsigned pk_enc(float f) {
  unsigned short hb = bf16_rne(f);
  float fh = __uint_as_float((unsigned)hb << 16);
  unsigned short lb = bf16_rne(f - fh);
  return ((unsigned)hb << 16) | (unsigned)lb;
}
__device__ __forceinline__ float pk_dec(unsigned p) {
  return __uint_as_float(p & 0xffff0000u) + __uint_as_float(p << 16);
}
__device__ __forceinline__ float sigm(float x) { return 1.f / (1.f + __expf(-x)); }
__device__ __forceinline__ float tanh_f(float x) { return 1.f - 2.f / (__expf(2.f * x) + 1.f); }
__device__ __forceinline__ f32x4 xor8(f32x4 v) {
  f32x4 r;
  r[0] = __shfl_xor(v[0], 8, 64); r[1] = __shfl_xor(v[1], 8, 64);
  r[2] = __shfl_xor(v[2], 8, 64); r[3] = __shfl_xor(v[3], 8, 64);
  return r;
}

// read partner half slab (2048 u64), tag-check, stage hi/lo planes
__device__ __forceinline__ bool stage_half(const unsigned long long* __restrict__ src,
                                           unsigned tagExp, int dhalf, int tid, char* smem) {
  bool ok = true;
#pragma unroll
  for (int k2 = 0; k2 < 4; ++k2) {
    unsigned long long x = __hip_atomic_load(src + k2 * 512 + tid,
                                             __ATOMIC_RELAXED, __HIP_MEMORY_SCOPE_AGENT);
    ok &= ((unsigned)(x >> 32) == tagExp);
    int e = k2 * 512 + tid;
    int m = e >> 7, c = dhalf * 128 + (e & 127);
    unsigned p = (unsigned)x;
    *(short*)(smem + HA_HI + m * 528 + c * 2) = (short)(p >> 16);
    *(short*)(smem + HA_LO + m * 528 + c * 2) = (short)(p & 0xffffu);
  }
  return ok;
}

__global__ void zero_ws(unsigned* __restrict__ ws) {
  int i = blockIdx.x * 512 + threadIdx.x;
  if (i < ZERO_WORDS) ws[i] = 0u;
}

__global__ void out_reduce(const unsigned* __restrict__ ws,
                           const float* __restrict__ b_out, float* __restrict__ out) {
  int idx = blockIdx.x * 512 + threadIdx.x;
  if (idx >= 64 * Sz) return;
  int b = idx >> 11, t = idx & 2047;
  int g = b >> 4, m = b & 15;
  const float* gh = (const float*)(ws + GH_WORD);
  out[idx] = b_out[0] + gh[((size_t)(g * 2 + 0) * Sz + t) * 16 + m]
                      + gh[((size_t)(g * 2 + 1) * Sz + t) * 16 + m];
}

__global__ __launch_bounds__(512, 2) void lstm_v3(
    const float* __restrict__ xin, const float* __restrict__ W_in,
    const float* __restrict__ b_in, const float* __restrict__ W_ih0,
    const float* __restrict__ W_hh0, const float* __restrict__ b_ih0,
    const float* __restrict__ b_hh0, const float* __restrict__ W_ih1,
    const float* __restrict__ W_hh1, const float* __restrict__ b_ih1,
    const float* __restrict__ b_hh1, const float* __restrict__ W_out,
    const float* __restrict__ b_out, unsigned* __restrict__ ws) {
  const int bx = blockIdx.x;
  if (bx >= 24) return;
  const int role = bx >> 3;      // 0=chainL0, 1=helper(ix1), 2=chainL1
  const int gh = bx & 7;
  const int g = gh >> 1, h = gh & 1;
  const int tid = (int)threadIdx.x;
  const int w = tid >> 6;        // wave 0..7
  const int lane = tid & 63;
  const int q = lane >> 4;       // quad
  const int n16 = lane & 15;
  const int n3 = n16 & 7;
  const int hf = n16 >> 3;       // 0: i/g-cols, 1: f/o-cols

  __shared__ __align__(16) char smem[SMEM_BYTES];

  unsigned long long* const ring = (unsigned long long*)ws;
  unsigned* const cfm = ws + CF_WORD;       // mdcf[gh]
  unsigned* const cfc = ws + CF_WORD + 8;   // c1cf[gh]
  float* const ghout = (float*)(ws + GH_WORD);
  float* const pout = (float*)(smem + POUT_LDS);

  // ---------------- startup: persistent weight fragments ----------------
  // wave w owns cols colg(j) = h*128 + w*16 + j*8 + n3 for j in {0,1}.
  // frag (j,u): n16<8 -> gate u*2 (i or g), n16>=8 -> gate u*2+1 (f or o).
  short8 wf[2][2][8];
  const float* Wrec = (role == 0) ? W_hh0 : (role == 1) ? W_ih1 : W_hh1;
#pragma unroll
  for (int j = 0; j < 2; ++j)
#pragma unroll
    for (int u = 0; u < 2; ++u) {
      const int row = (u * 2 + hf) * 256 + h * 128 + w * 16 + j * 8 + n3;
#pragma unroll
      for (int kt = 0; kt < 8; ++kt) {
        const float* src = Wrec + (size_t)row * 256 + kt * 32 + q * 8;
        union { short8 v; unsigned short s[8]; } fr;
#pragma unroll
        for (int z = 0; z < 8; ++z) fr.s[z] = bf16_rne(src[z]);
        wf[j][u][kt] = fr.v;
      }
    }

  short8 wfc[2][2][2];           // role0: W_comb = W_ih0 @ W_in (K=40 pad 64)
  float b8[2][4];                // role0: per-col gate biases (i,f,g,o)
  float bias4[2][2];             // role1
  float wo[2] = {0.f, 0.f};      // role2
  if (role == 0) {
#pragma unroll
    for (int j = 0; j < 2; ++j)
#pragma unroll
      for (int u = 0; u < 2; ++u) {
        const int row = (u * 2 + hf) * 256 + h * 128 + w * 16 + j * 8 + n3;
        const float* wr = W_ih0 + (size_t)row * 128;
        float s0[8] = {0, 0, 0, 0, 0, 0, 0, 0};
        float s1[8] = {0, 0, 0, 0, 0, 0, 0, 0};
        for (int e = 0; e < 128; ++e) {
          float wv = wr[e];
          const float* wi = W_in + e * 40;
#pragma unroll
          for (int z = 0; z < 8; ++z) s0[z] += wv * wi[q * 8 + z];
          if (q == 0) {
#pragma unroll
            for (int z = 0; z < 8; ++z) s1[z] += wv * wi[32 + z];
          }
        }
        union { short8 v; unsigned short s[8]; } f0, f1;
#pragma unroll
        for (int z = 0; z < 8; ++z) {
          f0.s[z] = bf16_rne(s0[z]);
          f1.s[z] = (q == 0) ? bf16_rne(s1[z]) : (unsigned short)0;
        }
        wfc[j][u][0] = f0.v;
        wfc[j][u][1] = f1.v;
      }
#pragma unroll
    for (int j = 0; j < 2; ++j) {
      const int colg = h * 128 + w * 16 + j * 8 + n3;
#pragma unroll
      for (int G = 0; G < 4; ++G) {
        const int row = G * 256 + colg;
        float s = b_ih0[row] + b_hh0[row];
        const float* wr = W_ih0 + (size_t)row * 128;
        for (int e = 0; e < 128; ++e) s += wr[e] * b_in[e];
        b8[j][G] = s;
      }
    }
  } else if (role == 1) {
#pragma unroll
    for (int j = 0; j < 2; ++j)
#pragma unroll
      for (int u = 0; u < 2; ++u) {
        const int row = (u * 2 + hf) * 256 + h * 128 + w * 16 + j * 8 + n3;
        bias4[j][u] = b_ih1[row] + b_hh1[row];
      }
  } else {
#pragma unroll
    for (int j = 0; j < 2; ++j) wo[j] = W_out[h * 128 + w * 16 + j * 8 + n3];
  }

  // zero LDS planes (h(-1)=0); role0: zero IN planes (cols 40..63 stay 0)
  for (int i = tid; i < 4224; i += 512) ((int*)smem)[i] = 0;
  if (role == 0)
    for (int i = tid; i < 1152; i += 512) ((int*)(smem + IN_HI))[i] = 0;
  __syncthreads();
  if (role == 0 && tid < 160) {  // stage x(0)
    int bb = tid / 10, f4 = tid - bb * 10;
    float4 xv = *(const float4*)(xin + ((size_t)(g * 16 + bb) * Sz) * 40 + f4 * 4);
#pragma unroll
    for (int cc = 0; cc < 4; ++cc) {
      float f = ((const float*)&xv)[cc];
      unsigned p = pk_enc(f);
      int col = f4 * 4 + cc;
      *(short*)(smem + IN_HI + bb * 144 + col * 2) = (short)(p >> 16);
      *(short*)(smem + IN_LO + bb * 144 + col * 2) = (short)(p & 0xffffu);
    }
  }

  float cst[2][2] = {{0.f, 0.f}, {0.f, 0.f}};

  // ================= role 0: chain L0 =================
  if (role == 0) {
#pragma unroll 1
    for (int t = 0; t < Sz; ++t) {
      float4 xv;
      const bool hasx = (t + 1 < Sz) && (tid < 160);
      int bb = 0, f4 = 0;
      if (hasx) {
        bb = tid / 10; f4 = tid - bb * 10;
        xv = *(const float4*)(xin + ((size_t)(g * 16 + bb) * Sz + (t + 1)) * 40 + f4 * 4);
      }
      const unsigned long long* srcP =
          ring + ((size_t)(g * 8 + ((t + 7) & 7)) * 2 + (1 - h)) * 2048;
      bool okP = false, okM = (tid >= 2);
      int fails = 0;
      for (;;) {
        if (!okP) okP = stage_half(srcP, (unsigned)t, 1 - h, tid, smem);
        if (!okM) {
          unsigned c = __hip_atomic_load(cfm + g * 2 + tid, __ATOMIC_RELAXED,
                                         __HIP_MEMORY_SCOPE_AGENT);
          okM = ((int)c >= t - 7);
        }
        if (__syncthreads_and(okP && okM)) break;
        if (++fails > 2) __builtin_amdgcn_s_sleep(1);
      }
      // MFMA: input (K=64) + recurrent (K=256), hi/lo split
      f32x4 acc[2][2] = {{{0,0,0,0},{0,0,0,0}},{{0,0,0,0},{0,0,0,0}}};
#pragma unroll
      for (int kt = 0; kt < 2; ++kt) {
        short8 aH = *(const short8*)(smem + IN_HI + n16 * 144 + (kt * 32 + q * 8) * 2);
        short8 aL = *(const short8*)(smem + IN_LO + n16 * 144 + (kt * 32 + q * 8) * 2);
#pragma unroll
        for (int j = 0; j < 2; ++j)
#pragma unroll
          for (int u = 0; u < 2; ++u) {
            acc[j][u] = __builtin_amdgcn_mfma_f32_16x16x32_bf16(aH, wfc[j][u][kt], acc[j][u], 0, 0, 0);
            acc[j][u] = __builtin_amdgcn_mfma_f32_16x16x32_bf16(aL, wfc[j][u][kt], acc[j][u], 0, 0, 0);
          }
      }
#pragma unroll
      for (int kt = 0; kt < 8; ++kt) {
        short8 aH = *(const short8*)(smem + HA_HI + n16 * 528 + (kt * 32 + q * 8) * 2);
        short8 aL = *(const short8*)(smem + HA_LO + n16 * 528 + (kt * 32 + q * 8) * 2);
#pragma unroll
        for (int j = 0; j < 2; ++j)
#pragma unroll
          for (int u = 0; u < 2; ++u) {
            acc[j][u] = __builtin_amdgcn_mfma_f32_16x16x32_bf16(aH, wf[j][u][kt], acc[j][u], 0, 0, 0);
            acc[j][u] = __builtin_amdgcn_mfma_f32_16x16x32_bf16(aL, wf[j][u][kt], acc[j][u], 0, 0, 0);
          }
      }
      __syncthreads();  // MFMA reads done -> safe to restage LDS
      // epilogue
      unsigned long long* dst = ring + ((size_t)(g * 8 + (t & 7)) * 2 + h) * 2048;
      const unsigned long long tagW = ((unsigned long long)(unsigned)(t + 1)) << 32;
#pragma unroll
      for (int j = 0; j < 2; ++j) {
        f32x4 a0 = acc[j][0], a1 = acc[j][1];
        f32x4 x0 = xor8(a0), x1 = xor8(a1);
#pragma unroll
        for (int rs = 0; rs < 2; ++rs) {
          const int r = hf * 2 + rs;
          float pi = hf ? x0[r] : a0[r];
          float pf = hf ? a0[r] : x0[r];
          float pg = hf ? x1[r] : a1[r];
          float po = hf ? a1[r] : x1[r];
          pi = sigm(pi + b8[j][0]); pf = sigm(pf + b8[j][1]);
          pg = tanh_f(pg + b8[j][2]); po = sigm(po + b8[j][3]);
          float c = pf * cst[j][rs] + pi * pg;
          cst[j][rs] = c;
          float hv = po * tanh_f(c);
          const int m = q * 4 + r, colL = w * 16 + j * 8 + n3;
          unsigned p = pk_enc(hv);
          __hip_atomic_store(dst + m * 128 + colL, tagW | p,
                             __ATOMIC_RELAXED, __HIP_MEMORY_SCOPE_AGENT);
          const int cg = h * 128 + colL;
          *(short*)(smem + HA_HI + m * 528 + cg * 2) = (short)(p >> 16);
          *(short*)(smem + HA_LO + m * 528 + cg * 2) = (short)(p & 0xffffu);
        }
      }
      if (hasx) {
#pragma unroll
        for (int cc = 0; cc < 4; ++cc) {
          float f = ((const float*)&xv)[cc];
          unsigned p = pk_enc(f);
          int col = f4 * 4 + cc;
          *(short*)(smem + IN_HI + bb * 144 + col * 2) = (short)(p >> 16);
          *(short*)(smem + IN_LO + bb * 144 + col * 2) = (short)(p & 0xffffu);
        }
      }
    }
  }
  // ================= role 1: helper ix1 = W_ih1 @ h0 =================
  else if (role == 1) {
#pragma unroll 1
    for (int t = 0; t < Sz; ++t) {
      const unsigned long long* srcH = ring + ((size_t)(g * 8 + (t & 7)) * 2) * 2048;
      bool okH = false, okC = (tid != 0);
      int fails = 0;
      for (;;) {
        if (!okH) {
          bool ok = true;
#pragma unroll
          for (int k2 = 0; k2 < 8; ++k2) {
            unsigned long long x = __hip_atomic_load(srcH + k2 * 512 + tid,
                                                     __ATOMIC_RELAXED, __HIP_MEMORY_SCOPE_AGENT);
            ok &= ((unsigned)(x >> 32) == (unsigned)(t + 1));
            int e = k2 * 512 + tid;
            int hh = e >> 11, ee = e & 2047;
            int m = ee >> 7, c = hh * 128 + (ee & 127);
            unsigned p = (unsigned)x;
            *(short*)(smem + HA_HI + m * 528 + c * 2) = (short)(p >> 16);
            *(short*)(smem + HA_LO + m * 528 + c * 2) = (short)(p & 0xffffu);
          }
          okH = ok;
        }
        if (!okC) {
          unsigned c = __hip_atomic_load(cfc + gh, __ATOMIC_RELAXED, __HIP_MEMORY_SCOPE_AGENT);
          okC = ((int)c >= t - 7);
        }
        if (__syncthreads_and(okH && okC)) break;
        if (++fails > 2) __builtin_amdgcn_s_sleep(1);
      }
      if (tid == 0)
        __hip_atomic_store(cfm + gh, (unsigned)(t + 1), __ATOMIC_RELAXED, __HIP_MEMORY_SCOPE_AGENT);
      f32x4 acc[2][2] = {{{0,0,0,0},{0,0,0,0}},{{0,0,0,0},{0,0,0,0}}};
#pragma unroll
      for (int kt = 0; kt < 8; ++kt) {
        short8 aH = *(const short8*)(smem + HA_HI + n16 * 528 + (kt * 32 + q * 8) * 2);
        short8 aL = *(const short8*)(smem + HA_LO + n16 * 528 + (kt * 32 + q * 8) * 2);
#pragma unroll
        for (int j = 0; j < 2; ++j)
#pragma unroll
          for (int u = 0; u < 2; ++u) {
            acc[j][u] = __builtin_amdgcn_mfma_f32_16x16x32_bf16(aH, wf[j][u][kt], acc[j][u], 0, 0, 0);
            acc[j][u] = __builtin_amdgcn_mfma_f32_16x16x32_bf16(aL, wf[j][u][kt], acc[j][u], 0, 0, 0);
          }
      }
      __syncthreads();
      unsigned long long* dst = ring + IX_BASE + ((size_t)(g * 8 + (t & 7)) * 2 + h) * 8192;
      const unsigned long long tagW = ((unsigned long long)(unsigned)(t + 1)) << 32;
#pragma unroll
      for (int j = 0; j < 2; ++j)
#pragma unroll
        for (int u = 0; u < 2; ++u) {
          const int G = u * 2 + hf;
          const int colL = w * 16 + j * 8 + n3;
          const float bb = bias4[j][u];
#pragma unroll
          for (int r = 0; r < 4; ++r) {
            float val = acc[j][u][r] + bb;
            __hip_atomic_store(dst + ((size_t)(G * 128 + colL) * 16 + q * 4 + r),
                               tagW | pk_enc(val), __ATOMIC_RELAXED, __HIP_MEMORY_SCOPE_AGENT);
          }
        }
    }
  }
  // ================= role 2: chain L1 =================
  else {
#pragma unroll 1
    for (int t = 0; t < Sz; ++t) {
      const unsigned long long* srcP =
          ring + H1_BASE + ((size_t)(g * 4 + ((t + 3) & 3)) * 2 + (1 - h)) * 2048;
      const unsigned long long* srcX =
          ring + IX_BASE + ((size_t)(g * 8 + (t & 7)) * 2 + h) * 8192;
      bool okP = false, okX = false;
      int fails = 0;
      unsigned ixp[4][2][2];
      for (;;) {
        if (!okP) okP = stage_half(srcP, (unsigned)t, 1 - h, tid, smem);
        if (!okX) {
          bool ok = true;
#pragma unroll
          for (int G = 0; G < 4; ++G)
#pragma unroll
            for (int j = 0; j < 2; ++j)
#pragma unroll
              for (int rs = 0; rs < 2; ++rs) {
                const size_t word = (size_t)(G * 128 + w * 16 + j * 8 + n3) * 16
                                    + q * 4 + hf * 2 + rs;
                unsigned long long x = __hip_atomic_load(srcX + word,
                                                         __ATOMIC_RELAXED, __HIP_MEMORY_SCOPE_AGENT);
                ok &= ((unsigned)(x >> 32) == (unsigned)(t + 1));
                ixp[G][j][rs] = (unsigned)x;
              }
          okX = ok;
        }
        if (__syncthreads_and(okP && okX)) break;
        if (++fails > 2) __builtin_amdgcn_s_sleep(1);
      }
      if (tid == 0)
        __hip_atomic_store(cfc + gh, (unsigned)(t + 1), __ATOMIC_RELAXED, __HIP_MEMORY_SCOPE_AGENT);
      // flush out-partials of step t-1 (safe: all waves past epilogue t-1)
      if (w == 0 && lane < 16 && t > 0) {
        float s = 0.f;
#pragma unroll
        for (int ww = 0; ww < 8; ++ww) s += pout[((t - 1) & 1) * 128 + ww * 16 + lane];
        ghout[((size_t)(g * 2 + h) * Sz + (t - 1)) * 16 + lane] = s;
      }
      f32x4 acc[2][2] = {{{0,0,0,0},{0,0,0,0}},{{0,0,0,0},{0,0,0,0}}};
#pragma unroll
      for (int kt = 0; kt < 8; ++kt) {
        short8 aH = *(const short8*)(smem + HA_HI + n16 * 528 + (kt * 32 + q * 8) * 2);
        short8 aL = *(const short8*)(smem + HA_LO + n16 * 528 + (kt * 32 + q * 8) * 2);
#pragma unroll
        for (int j = 0; j < 2; ++j)
#pragma unroll
          for (int u = 0; u < 2; ++u) {
            acc[j][u] = __builtin_amdgcn_mfma_f32_16x16x32_bf16(aH, wf[j][u][kt], acc[j][u], 0, 0, 0);
            acc[j][u] = __builtin_amdgcn_mfma_f32_16x16x32_bf16(aL, wf[j][u][kt], acc[j][u], 0, 0, 0);
          }
      }
      __syncthreads();
      unsigned long long* dst = ring + H1_BASE + ((size_t)(g * 4 + (t & 3)) * 2 + h) * 2048;
      const unsigned long long tagW = ((unsigned long long)(unsigned)(t + 1)) << 32;
      float vj[2] = {0.f, 0.f};
#pragma unroll
      for (int j = 0; j < 2; ++j) {
        f32x4 a0 = acc[j][0], a1 = acc[j][1];
        f32x4 x0 = xor8(a0), x1 = xor8(a1);
#pragma unroll
        for (int rs = 0; rs < 2; ++rs) {
          const int r = hf * 2 + rs;
          float pi = (hf ? x0[r] : a0[r]) + pk_dec(ixp[0][j][rs]);
          float pf = (hf ? a0[r] : x0[r]) + pk_dec(ixp[1][j][rs]);
          float pg = (hf ? x1[r] : a1[r]) + pk_dec(ixp[2][j][rs]);
          float po = (hf ? a1[r] : x1[r]) + pk_dec(ixp[3][j][rs]);
          pi = sigm(pi); pf = sigm(pf); pg = tanh_f(pg); po = sigm(po);
          float c = pf * cst[j][rs] + pi * pg;
          cst[j][rs] = c;
          float hv = po * tanh_f(c);
          const int m = q * 4 + r, colL = w * 16 + j * 8 + n3;
          unsigned p = pk_enc(hv);
          __hip_atomic_store(dst + m * 128 + colL, tagW | p,
                             __ATOMIC_RELAXED, __HIP_MEMORY_SCOPE_AGENT);
          const int cg = h * 128 + colL;
          *(short*)(smem + HA_HI + m * 528 + cg * 2) = (short)(p >> 16);
          *(short*)(smem + HA_LO + m * 528 + cg * 2) = (short)(p & 0xffffu);
          vj[rs] += hv * wo[j];
        }
      }
#pragma unroll
      for (int msk = 1; msk <= 4; msk <<= 1) {
        vj[0] += __shfl_xor(vj[0], msk, 64);
        vj[1] += __shfl_xor(vj[1], msk, 64);
      }
      if (n3 == 0) {
        const int m0 = q * 4 + hf * 2;
        pout[(t & 1) * 128 + w * 16 + m0] = vj[0];
        pout[(t & 1) * 128 + w * 16 + m0 + 1] = vj[1];
      }
    }
    __syncthreads();
    if (w == 0 && lane < 16) {
      float s = 0.f;
#pragma unroll
      for (int ww = 0; ww < 8; ++ww) s += pout[((Sz - 1) & 1) * 128 + ww * 16 + lane];
      ghout[((size_t)(g * 2 + h) * Sz + (Sz - 1)) * 16 + lane] = s;
    }
  }
}

extern "C" void kernel_launch(void* const* d_in, const int* in_sizes, int n_in,
                              void* d_out, int out_size, void* d_ws, size_t ws_size,
                              hipStream_t stream) {
  const float* xin   = (const float*)d_in[0];
  const float* W_in  = (const float*)d_in[1];
  const float* b_in  = (const float*)d_in[2];
  const float* W_ih0 = (const float*)d_in[3];
  const float* W_hh0 = (const float*)d_in[4];
  const float* b_ih0 = (const float*)d_in[5];
  const float* b_hh0 = (const float*)d_in[6];
  const float* W_ih1 = (const float*)d_in[7];
  const float* W_hh1 = (const float*)d_in[8];
  const float* b_ih1 = (const float*)d_in[9];
  const float* b_hh1 = (const float*)d_in[10];
  const float* W_out = (const float*)d_in[11];
  const float* b_out = (const float*)d_in[12];
  float* out = (float*)d_out;
  unsigned* ws = (unsigned*)d_ws;

  zero_ws<<<(ZERO_WORDS + 511) / 512, 512, 0, stream>>>(ws);
  lstm_v3<<<24, 512, 0, stream>>>(xin, W_in, b_in, W_ih0, W_hh0, b_ih0, b_hh0,
                                  W_ih1, W_hh1, b_ih1, b_hh1, W_out, b_out, ws);
  out_reduce<<<(64 * Sz + 511) / 512, 512, 0, stream>>>(ws, b_out, out);
}

// Round 4
// 11845.082 us; speedup vs baseline: 1.6415x; 1.6415x over previous
//
#include <hip/hip_runtime.h>

// 2-layer LSTM, B=64, S=2048, F=40, EMB=128, HID=256 — R4 merged-layer design.
// 32 blocks = 4 groups(16 batches) x 8 slices(32 h-cols). Each block holds
// bf16 B-frags of W_hh0, W_hh1, W_ih1 (its 128 gate-rows each) + folded
// W_comb = W_ih0@W_in. Superstep t: compute h0(t) and h1(t-1) — all inputs
// were published at superstep t-1 => exactly ONE exchange round-trip per
// superstep. Tagged-u64 relaxed agent atomics; per-thread sticky polls (no
// barrier in retry loop); gates combined in-register via shfl_xor (2
// barriers/superstep); out-proj -> ghout -> post reduce (no atomics).

#define Sz 2048
#define D 4

typedef __attribute__((ext_vector_type(8))) short short8;
typedef __attribute__((ext_vector_type(4))) float f32x4;

// ws layout
#define R1_U64 65536          // h1 ring base (u64 units); h0 ring at 0
#define GH_WORD 262144        // ghout base (u32 units): [g][p][Sz][16] f32
#define ZERO_WORDS 262144     // only rings need zeroing

// LDS byte offsets
#define H0_HI 0
#define H0_LO 8448
#define H1_HI 16896
#define H1_LO 25344
#define IN_HI 33792
#define IN_LO 36096
#define POUT  38400           // [2][8][16] f32 = 1024 B
#define SMEM_BYTES 39424

__device__ __forceinline__ unsigned short bf16_rne(float f) {
  unsigned u = __float_as_uint(f);
  u += 0x7FFFu + ((u >> 16) & 1u);
  return (unsigned short)(u >> 16);
}
__device__ __forceinline__ unsigned pk_enc(float f) {
  unsigned short hb = bf16_rne(f);
  float fh = __uint_as_float((unsigned)hb << 16);
  unsigned short lb = bf16_rne(f - fh);
  return ((unsigned)hb << 16) | (unsigned)lb;
}

__global__ void zero_ws(unsigned* __restrict__ ws) {
  int i = blockIdx.x * 512 + threadIdx.x;
  if (i < ZERO_WORDS) ws[i] = 0u;
}

__global__ void out_reduce(const unsigned* __restrict__ ws,
                           const float* __restrict__ b_out, float* __restrict__ out) {
  int idx = blockIdx.x * 512 + threadIdx.x;
  if (idx >= 64 * Sz) return;
  int b = idx >> 11, t = idx & 2047;
  int g = b >> 4, m = b & 15;
  const float* gh = (const float*)(ws + GH_WORD);
  float s = b_out[0];
#pragma unroll
  for (int p = 0; p < 8; ++p)
    s += gh[((size_t)(g * 8 + p) * Sz + t) * 16 + m];
  out[idx] = s;
}

__global__ __launch_bounds__(512, 2) void lstm_v4(
    const float* __restrict__ xin, const float* __restrict__ W_in,
    const float* __restrict__ b_in, const float* __restrict__ W_ih0,
    const float* __restrict__ W_hh0, const float* __restrict__ b_ih0,
    const float* __restrict__ b_hh0, const float* __restrict__ W_ih1,
    const float* __restrict__ W_hh1, const float* __restrict__ b_ih1,
    const float* __restrict__ b_hh1, const float* __restrict__ W_out,
    const float* __restrict__ b_out, unsigned* __restrict__ ws) {
  const int bx = blockIdx.x;
  if (bx >= 32) return;
  const int g = bx & 3, p = bx >> 2;
  const int tid = (int)threadIdx.x;
  const int w = tid >> 6;          // wave 0..7
  const int lane = tid & 63;
  const int q = lane >> 4;         // quad 0..3 (K-sub / batch-sub)
  const int n16 = lane & 15;       // B-frag row index
  const int gidx = n16 >> 2;       // gate 0..3 (i,f,g,o)
  const int c4 = n16 & 3;          // col-within-wave 0..3

  __shared__ __align__(16) char smem[SMEM_BYTES];

  // this lane's gate-row: gate*256 + p*32 + w*4 + c4
  const int mycol = p * 32 + w * 4 + c4;           // h column 0..255
  const int myrow = gidx * 256 + mycol;            // gate row 0..1023

  // ---------------- persistent weight fragments ----------------
  short8 wf0[8], wf1[8], wfi[8];   // W_hh0, W_hh1, W_ih1 (K=256: 8 kt)
#pragma unroll
  for (int kt = 0; kt < 8; ++kt) {
    const float* s0 = W_hh0 + (size_t)myrow * 256 + kt * 32 + q * 8;
    const float* s1 = W_hh1 + (size_t)myrow * 256 + kt * 32 + q * 8;
    const float* si = W_ih1 + (size_t)myrow * 256 + kt * 32 + q * 8;
    union { short8 v; unsigned short s[8]; } f0, f1, fi;
#pragma unroll
    for (int j = 0; j < 8; ++j) {
      f0.s[j] = bf16_rne(s0[j]);
      f1.s[j] = bf16_rne(s1[j]);
      fi.s[j] = bf16_rne(si[j]);
    }
    wf0[kt] = f0.v; wf1[kt] = f1.v; wfi[kt] = fi.v;
  }
  // W_comb = W_ih0 @ W_in (K=40 padded to 64) + folded L0 bias
  short8 wfc[2];
  float bL0, bL1, wo;
  {
    float sv[2][8];
#pragma unroll
    for (int kt = 0; kt < 2; ++kt)
#pragma unroll
      for (int j = 0; j < 8; ++j) sv[kt][j] = 0.f;
    float bacc = 0.f;
    const float* wr = W_ih0 + (size_t)myrow * 128;
    for (int e = 0; e < 128; ++e) {
      float wv = wr[e];
      const float* wi = W_in + e * 40;
      bacc += wv * b_in[e];
#pragma unroll
      for (int j = 0; j < 8; ++j) {
        int k0 = q * 8 + j;
        sv[0][j] += wv * wi[k0];
        int k1 = 32 + q * 8 + j;
        if (k1 < 40) sv[1][j] += wv * wi[k1];
      }
    }
    union { short8 v; unsigned short s[8]; } c0u, c1u;
#pragma unroll
    for (int j = 0; j < 8; ++j) {
      c0u.s[j] = bf16_rne(sv[0][j]);
      c1u.s[j] = (32 + q * 8 + j < 40) ? bf16_rne(sv[1][j]) : (unsigned short)0;
    }
    wfc[0] = c0u.v; wfc[1] = c1u.v;
    bL0 = b_ih0[myrow] + b_hh0[myrow] + bacc;
    bL1 = b_ih1[myrow] + b_hh1[myrow];
    wo = W_out[mycol];
  }

  // zero LDS h/IN planes (h(-1)=h1(-2)=0; IN cols 40..63 stay 0)
  for (int i = tid; i < 9600; i += 512) ((int*)smem)[i] = 0;
  __syncthreads();
  const int bb = tid / 10, f4 = tid - (tid / 10) * 10;  // x-stager coords
  if (tid < 160) {  // stage x(0)
    float4 xv = *(const float4*)(xin + ((size_t)(g * 16 + bb) * Sz) * 40 + f4 * 4);
#pragma unroll
    for (int cc = 0; cc < 4; ++cc) {
      unsigned pk = pk_enc(((const float*)&xv)[cc]);
      int col = f4 * 4 + cc;
      *(short*)(smem + IN_HI + bb * 144 + col * 2) = (short)(pk >> 16);
      *(short*)(smem + IN_LO + bb * 144 + col * 2) = (short)(pk & 0xffffu);
    }
  }

  float c0[4] = {0.f, 0.f, 0.f, 0.f};   // L0 cell state (4 batches of this col)
  float c1[4] = {0.f, 0.f, 0.f, 0.f};   // L1 cell state
  unsigned long long* const ring0 = (unsigned long long*)ws;
  unsigned long long* const ring1 = ring0 + R1_U64;
  float* const ghout = (float*)(ws + GH_WORD);
  float* const pout = (float*)(smem + POUT);
  const unsigned maskInit = (0xFFu & ~(1u << p)) | ((0xFFu & ~(1u << p)) << 8);
  const int stg_m = tid >> 5, stg_c = tid & 31;  // poll-stage coords

#pragma unroll 1
  for (int t = 0; t <= Sz; ++t) {
    // prefetch x(t+1) (consumed next superstep; latency hidden across step)
    float4 xv;
    const bool hasx = (t + 1 < Sz) && (tid < 160);
    if (hasx)
      xv = *(const float4*)(xin + ((size_t)(g * 16 + bb) * Sz + (t + 1)) * 40 + f4 * 4);

    // ---- single poll: everything needed was published at superstep t-1 ----
    if (t > 0) {
      const unsigned tagE = (unsigned)t;
      const unsigned long long* s0 =
          ring0 + ((size_t)(g * D + ((t - 1) & 3)) * 8) * 512;
      const unsigned long long* s1 =
          ring1 + ((size_t)(g * D + ((t - 1) & 3)) * 8) * 512;
      unsigned pend = maskInit;
      int spin = 0;
      while (pend) {
        unsigned long long v0[8], v1[8];
#pragma unroll
        for (int k = 0; k < 8; ++k)
          if (pend & (1u << k))
            v0[k] = __hip_atomic_load(s0 + k * 512 + tid, __ATOMIC_RELAXED,
                                      __HIP_MEMORY_SCOPE_AGENT);
#pragma unroll
        for (int k = 0; k < 8; ++k)
          if (pend & (1u << (8 + k)))
            v1[k] = __hip_atomic_load(s1 + k * 512 + tid, __ATOMIC_RELAXED,
                                      __HIP_MEMORY_SCOPE_AGENT);
#pragma unroll
        for (int k = 0; k < 8; ++k) {
          if ((pend & (1u << k)) && (unsigned)(v0[k] >> 32) == tagE) {
            unsigned pk = (unsigned)v0[k];
            int c = k * 32 + stg_c;
            *(short*)(smem + H0_HI + stg_m * 528 + c * 2) = (short)(pk >> 16);
            *(short*)(smem + H0_LO + stg_m * 528 + c * 2) = (short)(pk & 0xffffu);
            pend &= ~(1u << k);
          }
          if ((pend & (1u << (8 + k))) && (unsigned)(v1[k] >> 32) == tagE) {
            unsigned pk = (unsigned)v1[k];
            int c = k * 32 + stg_c;
            *(short*)(smem + H1_HI + stg_m * 528 + c * 2) = (short)(pk >> 16);
            *(short*)(smem + H1_LO + stg_m * 528 + c * 2) = (short)(pk & 0xffffu);
            pend &= ~(1u << (8 + k));
          }
        }
        if (pend && ++spin > 2) __builtin_amdgcn_s_sleep(1);
      }
    }
    __syncthreads();  // A: all staging done

    // pipelined ghout flush (partials of h1(t-2), written at superstep t-1)
    if (w == 0 && lane < 16 && t >= 2) {
      const int buf = (t - 1) & 1;
      float s = 0.f;
#pragma unroll
      for (int ww = 0; ww < 8; ++ww) s += pout[buf * 32 * 4 / 4];  // placeholder avoided
      s = 0.f;
#pragma unroll
      for (int ww = 0; ww < 8; ++ww) s += ((float*)(smem + POUT))[buf * 128 + ww * 16 + lane];
      ghout[((size_t)(g * 8 + p) * Sz + (t - 2)) * 16 + lane] = s;
    }

    // ---- MFMA ----
    f32x4 acc0 = {0.f, 0.f, 0.f, 0.f};
    f32x4 acc1 = {0.f, 0.f, 0.f, 0.f};
    if (t < Sz) {
#pragma unroll
      for (int kt = 0; kt < 2; ++kt) {
        short8 aH = *(const short8*)(smem + IN_HI + n16 * 144 + (kt * 32 + q * 8) * 2);
        short8 aL = *(const short8*)(smem + IN_LO + n16 * 144 + (kt * 32 + q * 8) * 2);
        acc0 = __builtin_amdgcn_mfma_f32_16x16x32_bf16(aH, wfc[kt], acc0, 0, 0, 0);
        acc0 = __builtin_amdgcn_mfma_f32_16x16x32_bf16(aL, wfc[kt], acc0, 0, 0, 0);
      }
    }
#pragma unroll
    for (int kt = 0; kt < 8; ++kt) {
      short8 aH0 = *(const short8*)(smem + H0_HI + n16 * 528 + (kt * 32 + q * 8) * 2);
      short8 aL0 = *(const short8*)(smem + H0_LO + n16 * 528 + (kt * 32 + q * 8) * 2);
      if (t < Sz) {
        acc0 = __builtin_amdgcn_mfma_f32_16x16x32_bf16(aH0, wf0[kt], acc0, 0, 0, 0);
        acc0 = __builtin_amdgcn_mfma_f32_16x16x32_bf16(aL0, wf0[kt], acc0, 0, 0, 0);
      }
      if (t > 0) {
        acc1 = __builtin_amdgcn_mfma_f32_16x16x32_bf16(aH0, wfi[kt], acc1, 0, 0, 0);
        acc1 = __builtin_amdgcn_mfma_f32_16x16x32_bf16(aL0, wfi[kt], acc1, 0, 0, 0);
        short8 aH1 = *(const short8*)(smem + H1_HI + n16 * 528 + (kt * 32 + q * 8) * 2);
        short8 aL1 = *(const short8*)(smem + H1_LO + n16 * 528 + (kt * 32 + q * 8) * 2);
        acc1 = __builtin_amdgcn_mfma_f32_16x16x32_bf16(aH1, wf1[kt], acc1, 0, 0, 0);
        acc1 = __builtin_amdgcn_mfma_f32_16x16x32_bf16(aL1, wf1[kt], acc1, 0, 0, 0);
      }
    }
    __syncthreads();  // B: MFMA LDS reads complete

    // ---- epilogue ----
    const unsigned long long tagW = ((unsigned long long)(unsigned)(t + 1)) << 32;
    const bool b0 = gidx & 1, b1 = gidx & 2;
    const float sc = (gidx == 2) ? 2.f : 1.f;

    if (t < Sz) {  // L0: h0(t)
      unsigned pk0[4];
#pragma unroll
      for (int r = 0; r < 4; ++r) {
        float a = acc0[r] + bL0;
        float y = 1.f / (1.f + __expf(-a * sc));
        float v = fmaf(y, sc, 1.f - sc);
        float t1 = __shfl_xor(v, 4, 64);
        float t2 = __shfl_xor(v, 8, 64);
        float t3 = __shfl_xor(t1, 8, 64);
        float pi = b1 ? (b0 ? t3 : t2) : (b0 ? t1 : v);
        float pf = b1 ? (b0 ? t2 : t3) : (b0 ? v : t1);
        float pg = b1 ? (b0 ? t1 : v) : (b0 ? t3 : t2);
        float po = b1 ? (b0 ? v : t1) : (b0 ? t2 : t3);
        float c = pf * c0[r] + pi * pg;
        c0[r] = c;
        float th = 2.f / (1.f + __expf(-2.f * c)) - 1.f;
        pk0[r] = pk_enc(po * th);
      }
      unsigned long long* dst0 = ring0 + ((size_t)(g * D + (t & 3)) * 8 + p) * 512;
      if (gidx == 0) {
#pragma unroll
        for (int r = 0; r < 4; ++r)
          __hip_atomic_store(dst0 + (q * 4 + r) * 32 + w * 4 + c4, tagW | pk0[r],
                             __ATOMIC_RELAXED, __HIP_MEMORY_SCOPE_AGENT);
      } else if (gidx == 1) {
#pragma unroll
        for (int r = 0; r < 4; ++r) {
          int m = q * 4 + r;
          *(short*)(smem + H0_HI + m * 528 + mycol * 2) = (short)(pk0[r] >> 16);
          *(short*)(smem + H0_LO + m * 528 + mycol * 2) = (short)(pk0[r] & 0xffffu);
        }
      }
    }
    {  // L1: h1(t-1)  (t==0 publishes zeros = h1(-1))
      float h1v[4] = {0.f, 0.f, 0.f, 0.f};
      unsigned pk1[4] = {0u, 0u, 0u, 0u};
      if (t > 0) {
#pragma unroll
        for (int r = 0; r < 4; ++r) {
          float a = acc1[r] + bL1;
          float y = 1.f / (1.f + __expf(-a * sc));
          float v = fmaf(y, sc, 1.f - sc);
          float t1 = __shfl_xor(v, 4, 64);
          float t2 = __shfl_xor(v, 8, 64);
          float t3 = __shfl_xor(t1, 8, 64);
          float pi = b1 ? (b0 ? t3 : t2) : (b0 ? t1 : v);
          float pf = b1 ? (b0 ? t2 : t3) : (b0 ? v : t1);
          float pg = b1 ? (b0 ? t1 : v) : (b0 ? t3 : t2);
          float po = b1 ? (b0 ? v : t1) : (b0 ? t2 : t3);
          float c = pf * c1[r] + pi * pg;
          c1[r] = c;
          float th = 2.f / (1.f + __expf(-2.f * c)) - 1.f;
          h1v[r] = po * th;
          pk1[r] = pk_enc(h1v[r]);
        }
      }
      if (t < Sz) {
        unsigned long long* dst1 = ring1 + ((size_t)(g * D + (t & 3)) * 8 + p) * 512;
        if (gidx == 0) {
#pragma unroll
          for (int r = 0; r < 4; ++r)
            __hip_atomic_store(dst1 + (q * 4 + r) * 32 + w * 4 + c4, tagW | pk1[r],
                               __ATOMIC_RELAXED, __HIP_MEMORY_SCOPE_AGENT);
        } else if (gidx == 1) {
#pragma unroll
          for (int r = 0; r < 4; ++r) {
            int m = q * 4 + r;
            *(short*)(smem + H1_HI + m * 528 + mycol * 2) = (short)(pk1[r] >> 16);
            *(short*)(smem + H1_LO + m * 528 + mycol * 2) = (short)(pk1[r] & 0xffffu);
          }
        }
      }
      if (t > 0) {  // out-projection partial for h1(t-1)
        float vr[4];
#pragma unroll
        for (int r = 0; r < 4; ++r) {
          float v = h1v[r] * wo;
          v += __shfl_xor(v, 1, 64);
          v += __shfl_xor(v, 2, 64);
          vr[r] = v;
        }
        if (n16 == 12) {
#pragma unroll
          for (int r = 0; r < 4; ++r)
            ((float*)(smem + POUT))[(t & 1) * 128 + w * 16 + q * 4 + r] = vr[r];
        }
      }
    }
    if (hasx) {  // stage x(t+1)
#pragma unroll
      for (int cc = 0; cc < 4; ++cc) {
        unsigned pk = pk_enc(((const float*)&xv)[cc]);
        int col = f4 * 4 + cc;
        *(short*)(smem + IN_HI + bb * 144 + col * 2) = (short)(pk >> 16);
        *(short*)(smem + IN_LO + bb * 144 + col * 2) = (short)(pk & 0xffffu);
      }
    }
  }
  __syncthreads();
  if (w == 0 && lane < 16) {  // final flush: h1(Sz-1) partials
    float s = 0.f;
#pragma unroll
    for (int ww = 0; ww < 8; ++ww) s += ((float*)(smem + POUT))[(Sz & 1) * 128 + ww * 16 + lane];
    ghout[((size_t)(g * 8 + p) * Sz + (Sz - 1)) * 16 + lane] = s;
  }
}

extern "C" void kernel_launch(void* const* d_in, const int* in_sizes, int n_in,
                              void* d_out, int out_size, void* d_ws, size_t ws_size,
                              hipStream_t stream) {
  const float* xin   = (const float*)d_in[0];
  const float* W_in  = (const float*)d_in[1];
  const float* b_in  = (const float*)d_in[2];
  const float* W_ih0 = (const float*)d_in[3];
  const float* W_hh0 = (const float*)d_in[4];
  const float* b_ih0 = (const float*)d_in[5];
  const float* b_hh0 = (const float*)d_in[6];
  const float* W_ih1 = (const float*)d_in[7];
  const float* W_hh1 = (const float*)d_in[8];
  const float* b_ih1 = (const float*)d_in[9];
  const float* b_hh1 = (const float*)d_in[10];
  const float* W_out = (const float*)d_in[11];
  const float* b_out = (const float*)d_in[12];
  float* out = (float*)d_out;
  unsigned* ws = (unsigned*)d_ws;

  zero_ws<<<(ZERO_WORDS + 511) / 512, 512, 0, stream>>>(ws);
  lstm_v4<<<32, 512, 0, stream>>>(xin, W_in, b_in, W_ih0, W_hh0, b_ih0, b_hh0,
                                  W_ih1, W_hh1, b_ih1, b_hh1, W_out, b_out, ws);
  out_reduce<<<(64 * Sz + 511) / 512, 512, 0, stream>>>(ws, b_out, out);
}

// Round 5
// 10878.967 us; speedup vs baseline: 1.7873x; 1.0888x over previous
//
#include <hip/hip_runtime.h>

// 2-layer LSTM, B=64, S=2048, F=40, EMB=128, HID=256 — R5.
// 32 blocks = 4 groups x 8 slices(32 cols), 512 thr. Waves 0-3: layer0
// (wfA=W_hh0 on H0-plane, wfB=W_comb on IN-plane); waves 4-7: layer1
// (wfA=W_ih1 on H0-plane, wfB=W_hh1 on H1-plane). Each wave covers 8 cols
// (j=2). Superstep t computes h0(t)+h1(t-1): ONE exchange RT per superstep.
// LDS planes in MFMA-fragment order [kt][q][m] -> conflict-free ds_read_b128.
// Ring slabs [col][m] tagged-u64 relaxed agent atomics; paired-col b32 staging.

#define Sz 2048
#define D 4

typedef __attribute__((ext_vector_type(8))) short short8;
typedef __attribute__((ext_vector_type(4))) float f32x4;

#define R1_U64 65536          // ring1 base (u64); ring0 at 0 (each 512 KB)
#define GH_WORD 262144        // ghout base (u32): [g][p][Sz][16] f32

// LDS byte offsets (fragment-order planes: (kt*4+q)*16+m 16B units)
#define H0_HI 0
#define H0_LO 8192
#define H1_HI 16384
#define H1_LO 24576
#define IN_HI 32768
#define IN_LO 34816
#define POUT  36864           // [2][4][16] f32 = 512 B
#define SMEM_BYTES 37376

__device__ __forceinline__ unsigned short bf16_rne(float f) {
  unsigned u = __float_as_uint(f);
  u += 0x7FFFu + ((u >> 16) & 1u);
  return (unsigned short)(u >> 16);
}
__device__ __forceinline__ unsigned pk_enc(float f) {
  unsigned short hb = bf16_rne(f);
  float fh = __uint_as_float((unsigned)hb << 16);
  unsigned short lb = bf16_rne(f - fh);
  return ((unsigned)hb << 16) | (unsigned)lb;
}

__global__ void out_reduce(const unsigned* __restrict__ ws,
                           const float* __restrict__ b_out, float* __restrict__ out) {
  int idx = blockIdx.x * 512 + threadIdx.x;
  if (idx >= 64 * Sz) return;
  int b = idx >> 11, t = idx & 2047;
  int g = b >> 4, m = b & 15;
  const float* gh = (const float*)(ws + GH_WORD);
  float s = b_out[0];
#pragma unroll
  for (int p = 0; p < 8; ++p)
    s += gh[((size_t)(g * 8 + p) * Sz + t) * 16 + m];
  out[idx] = s;
}

__global__ __launch_bounds__(512, 1) void lstm_v5(
    const float* __restrict__ xin, const float* __restrict__ W_in,
    const float* __restrict__ b_in, const float* __restrict__ W_ih0,
    const float* __restrict__ W_hh0, const float* __restrict__ b_ih0,
    const float* __restrict__ b_hh0, const float* __restrict__ W_ih1,
    const float* __restrict__ W_hh1, const float* __restrict__ b_ih1,
    const float* __restrict__ b_hh1, const float* __restrict__ W_out,
    const float* __restrict__ b_out, unsigned* __restrict__ ws) {
  const int bx = blockIdx.x;
  if (bx >= 32) return;
  const int g = bx & 3, p = bx >> 2;
  const int tid = (int)threadIdx.x;
  const int w = tid >> 6;
  const int lane = tid & 63;
  const int q = lane >> 4, n16 = lane & 15;
  const int gidx = n16 >> 2, c4 = n16 & 3;
  const bool isL0 = (w < 4);
  const int wi = w & 3;
  const int colb = p * 32 + wi * 8;          // wave col base; col(j)=colb+j*4+c4

  __shared__ __align__(16) char smem[SMEM_BYTES];

  // ---------------- persistent weights ----------------
  // wfA multiplies H0-plane (L0: W_hh0, L1: W_ih1); wfB multiplies IN (L0,
  // kt<2, = W_comb) or H1 (L1, W_hh1).
  short8 wfA[2][8], wfB[2][8];
  float bb2[2], wo[2] = {0.f, 0.f};
  {
    const float* WA = isL0 ? W_hh0 : W_ih1;
#pragma unroll
    for (int j = 0; j < 2; ++j) {
      const int row = gidx * 256 + colb + j * 4 + c4;
#pragma unroll
      for (int kt = 0; kt < 8; ++kt) {
        const float* src = WA + (size_t)row * 256 + kt * 32 + q * 8;
        union { short8 v; unsigned short s[8]; } fr;
#pragma unroll
        for (int z = 0; z < 8; ++z) fr.s[z] = bf16_rne(src[z]);
        wfA[j][kt] = fr.v;
      }
      if (isL0) {
        float sv0[8], sv1[8];
#pragma unroll
        for (int z = 0; z < 8; ++z) { sv0[z] = 0.f; sv1[z] = 0.f; }
        float bacc = 0.f;
        const float* wr = W_ih0 + (size_t)row * 128;
        for (int e = 0; e < 128; ++e) {
          float wv = wr[e];
          const float* wiv = W_in + e * 40;
          bacc += wv * b_in[e];
#pragma unroll
          for (int z = 0; z < 8; ++z) sv0[z] += wv * wiv[q * 8 + z];
          if (q == 0) {
#pragma unroll
            for (int z = 0; z < 8; ++z) sv1[z] += wv * wiv[32 + z];
          }
        }
        union { short8 v; unsigned short s[8]; } f0, f1;
#pragma unroll
        for (int z = 0; z < 8; ++z) {
          f0.s[z] = bf16_rne(sv0[z]);
          f1.s[z] = (q == 0) ? bf16_rne(sv1[z]) : (unsigned short)0;
        }
        wfB[j][0] = f0.v; wfB[j][1] = f1.v;
        bb2[j] = b_ih0[row] + b_hh0[row] + bacc;
      } else {
#pragma unroll
        for (int kt = 0; kt < 8; ++kt) {
          const float* src = W_hh1 + (size_t)row * 256 + kt * 32 + q * 8;
          union { short8 v; unsigned short s[8]; } fr;
#pragma unroll
          for (int z = 0; z < 8; ++z) fr.s[z] = bf16_rne(src[z]);
          wfB[j][kt] = fr.v;
        }
        bb2[j] = b_ih1[row] + b_hh1[row];
        wo[j] = W_out[colb + j * 4 + c4];
      }
    }
  }

  // zero all LDS planes + pout (h(-1)=h1(-2)=0; IN cols 40..63 stay 0)
  for (int i = tid; i < SMEM_BYTES / 4; i += 512) ((int*)smem)[i] = 0;
  __syncthreads();
  const int xb = tid / 10, xf = tid - (tid / 10) * 10;
  if (tid < 160) {  // stage x(0) in fragment order
    float4 xv = *(const float4*)(xin + ((size_t)(g * 16 + xb) * Sz) * 40 + xf * 4);
    unsigned p0 = pk_enc(xv.x), p1 = pk_enc(xv.y), p2 = pk_enc(xv.z), p3 = pk_enc(xv.w);
    const int k0 = xf * 4;
    const int off = (k0 >> 3) * 256 + xb * 16 + (k0 & 7) * 2;
    *(unsigned*)(smem + IN_HI + off)     = (p0 >> 16) | (p1 & 0xFFFF0000u);
    *(unsigned*)(smem + IN_HI + off + 4) = (p2 >> 16) | (p3 & 0xFFFF0000u);
    *(unsigned*)(smem + IN_LO + off)     = (p0 & 0xFFFFu) | (p1 << 16);
    *(unsigned*)(smem + IN_LO + off + 4) = (p2 & 0xFFFFu) | (p3 << 16);
  }

  float cst[2][4] = {{0.f, 0.f, 0.f, 0.f}, {0.f, 0.f, 0.f, 0.f}};
  unsigned long long* const ring0 = (unsigned long long*)ws;
  unsigned long long* const ring1 = ring0 + R1_U64;
  unsigned long long* const ringMy = isL0 ? ring0 : ring1;
  float* const ghout = (float*)(ws + GH_WORD);
  float* const pout = (float*)(smem + POUT);
  char* const myHi = smem + (isL0 ? H0_HI : H1_HI);
  char* const myLo = smem + (isL0 ? H0_LO : H1_LO);

  // poll coords: thread = (m, cp); covers col-pairs gcol = 2*(cp&15)+32*slab,
  // slab = (cp>>4) + 2*i for i in 0..3, both rings.
  const int pm = tid & 15, cp = tid >> 4;
  const int i0 = cp >> 4;
  const int colL2 = 2 * (cp & 15);
  const int wbase = colL2 * 16 + pm;

#pragma unroll 1
  for (int t = 0; t <= Sz; ++t) {
    float4 xv;
    const bool hasx = (t + 1 < Sz) && (tid < 160);
    if (hasx)
      xv = *(const float4*)(xin + ((size_t)(g * 16 + xb) * Sz + (t + 1)) * 40 + xf * 4);

    // ---- single-RT poll + fragment-order staging ----
    if (t > 0) {
      const unsigned tagE = (unsigned)t;
      const unsigned long long* sl0 = ring0 + (size_t)((g * D + ((t - 1) & 3)) * 8) * 512;
      const unsigned long long* sl1 = ring1 + (size_t)((g * D + ((t - 1) & 3)) * 8) * 512;
      unsigned pend = 0;
#pragma unroll
      for (int b = 0; b < 8; ++b)
        if (i0 + 2 * (b & 3) != p) pend |= 1u << b;
      int spin = 0;
      while (pend) {
        unsigned long long va[8], vb[8];
#pragma unroll
        for (int b = 0; b < 8; ++b)
          if (pend & (1u << b)) {
            const unsigned long long* s = ((b >> 2) ? sl1 : sl0)
                + (size_t)(i0 + 2 * (b & 3)) * 512 + wbase;
            va[b] = __hip_atomic_load(s, __ATOMIC_RELAXED, __HIP_MEMORY_SCOPE_AGENT);
            vb[b] = __hip_atomic_load(s + 16, __ATOMIC_RELAXED, __HIP_MEMORY_SCOPE_AGENT);
          }
#pragma unroll
        for (int b = 0; b < 8; ++b)
          if (pend & (1u << b)) {
            if ((unsigned)(va[b] >> 32) == tagE && (unsigned)(vb[b] >> 32) == tagE) {
              const int gc = (i0 + 2 * (b & 3)) * 32 + colL2;
              const int off = (gc >> 3) * 256 + pm * 16 + (gc & 7) * 2;
              unsigned pa = (unsigned)va[b], pb = (unsigned)vb[b];
              char* ph = smem + ((b >> 2) ? H1_HI : H0_HI);
              char* pl = smem + ((b >> 2) ? H1_LO : H0_LO);
              *(unsigned*)(ph + off) = (pa >> 16) | (pb & 0xFFFF0000u);
              *(unsigned*)(pl + off) = (pa & 0xFFFFu) | (pb << 16);
              pend &= ~(1u << b);
            }
          }
        if (pend && ++spin > 4) __builtin_amdgcn_s_sleep(1);
      }
    }
    __syncthreads();  // A

    // pipelined ghout flush of h1(t-2) partials
    if (w == 0 && lane < 16 && t >= 2) {
      const int par = (t - 1) & 1;
      float s = pout[par * 64 + lane] + pout[par * 64 + 16 + lane]
              + pout[par * 64 + 32 + lane] + pout[par * 64 + 48 + lane];
      ghout[((size_t)(g * 8 + p) * Sz + (t - 2)) * 16 + lane] = s;
    }

    // ---- MFMA (conflict-free fragment reads) ----
    const bool act = isL0 ? (t < Sz) : (t > 0);
    f32x4 acc[2] = {{0.f, 0.f, 0.f, 0.f}, {0.f, 0.f, 0.f, 0.f}};
    if (act) {
      const int lb = lane * 16;
#pragma unroll
      for (int kt = 0; kt < 8; ++kt) {
        short8 aH = *(const short8*)(smem + H0_HI + kt * 1024 + lb);
        short8 aL = *(const short8*)(smem + H0_LO + kt * 1024 + lb);
        acc[0] = __builtin_amdgcn_mfma_f32_16x16x32_bf16(aH, wfA[0][kt], acc[0], 0, 0, 0);
        acc[0] = __builtin_amdgcn_mfma_f32_16x16x32_bf16(aL, wfA[0][kt], acc[0], 0, 0, 0);
        acc[1] = __builtin_amdgcn_mfma_f32_16x16x32_bf16(aH, wfA[1][kt], acc[1], 0, 0, 0);
        acc[1] = __builtin_amdgcn_mfma_f32_16x16x32_bf16(aL, wfA[1][kt], acc[1], 0, 0, 0);
      }
      const char* bh = isL0 ? (smem + IN_HI) : (smem + H1_HI);
      const char* bl = isL0 ? (smem + IN_LO) : (smem + H1_LO);
      const int nktB = isL0 ? 2 : 8;
#pragma unroll
      for (int kt = 0; kt < 8; ++kt) {
        if (kt < nktB) {
          short8 aH = *(const short8*)(bh + kt * 1024 + lb);
          short8 aL = *(const short8*)(bl + kt * 1024 + lb);
          acc[0] = __builtin_amdgcn_mfma_f32_16x16x32_bf16(aH, wfB[0][kt], acc[0], 0, 0, 0);
          acc[0] = __builtin_amdgcn_mfma_f32_16x16x32_bf16(aL, wfB[0][kt], acc[0], 0, 0, 0);
          acc[1] = __builtin_amdgcn_mfma_f32_16x16x32_bf16(aH, wfB[1][kt], acc[1], 0, 0, 0);
          acc[1] = __builtin_amdgcn_mfma_f32_16x16x32_bf16(aL, wfB[1][kt], acc[1], 0, 0, 0);
        }
      }
    }
    __syncthreads();  // B: MFMA LDS reads done

    // ---- epilogue ----
    const unsigned long long tagW = ((unsigned long long)(unsigned)(t + 1)) << 32;
    const bool g0 = gidx & 1, g1 = gidx & 2;
    const float sc = (gidx == 2) ? 2.f : 1.f;
    float hv[2][4];
    unsigned pk[2][4];
#pragma unroll
    for (int j = 0; j < 2; ++j)
#pragma unroll
      for (int r = 0; r < 4; ++r) { hv[j][r] = 0.f; pk[j][r] = 0u; }
    if (act) {
#pragma unroll
      for (int j = 0; j < 2; ++j) {
#pragma unroll
        for (int r = 0; r < 4; ++r) {
          float a = acc[j][r] + bb2[j];
          float y = 1.f / (1.f + __expf(-a * sc));
          float v = fmaf(y, sc, 1.f - sc);
          float t1 = __shfl_xor(v, 4, 64);
          float t2 = __shfl_xor(v, 8, 64);
          float t3 = __shfl_xor(t1, 8, 64);
          float pi = g1 ? (g0 ? t3 : t2) : (g0 ? t1 : v);
          float pf = g1 ? (g0 ? t2 : t3) : (g0 ? v : t1);
          float pg = g1 ? (g0 ? t1 : v) : (g0 ? t3 : t2);
          float po = g1 ? (g0 ? v : t1) : (g0 ? t2 : t3);
          float c = pf * cst[j][r] + pi * pg;
          cst[j][r] = c;
          float th = 2.f / (1.f + __expf(-2.f * c)) - 1.f;
          hv[j][r] = po * th;
          pk[j][r] = pk_enc(hv[j][r]);
        }
      }
    }
    if (t < Sz) {
      if (gidx == 0) {
        unsigned long long* dst = ringMy + (size_t)((g * D + (t & 3)) * 8 + p) * 512;
#pragma unroll
        for (int j = 0; j < 2; ++j)
#pragma unroll
          for (int r = 0; r < 4; ++r)
            __hip_atomic_store(dst + (wi * 8 + j * 4 + c4) * 16 + q * 4 + r,
                               tagW | pk[j][r], __ATOMIC_RELAXED, __HIP_MEMORY_SCOPE_AGENT);
      } else if (gidx == 1) {
#pragma unroll
        for (int j = 0; j < 2; ++j) {
          const int col = colb + j * 4 + c4;
          const int off = (col >> 3) * 256 + (col & 7) * 2;
#pragma unroll
          for (int r = 0; r < 4; ++r) {
            const int o2 = off + (q * 4 + r) * 16;
            *(short*)(myHi + o2) = (short)(pk[j][r] >> 16);
            *(short*)(myLo + o2) = (short)(pk[j][r] & 0xffffu);
          }
        }
      }
    }
    if (!isL0 && t > 0) {  // out-projection partials for h1(t-1)
      float vr[4];
#pragma unroll
      for (int r = 0; r < 4; ++r) {
        float v = hv[0][r] * wo[0] + hv[1][r] * wo[1];
        v += __shfl_xor(v, 1, 64);
        v += __shfl_xor(v, 2, 64);
        vr[r] = v;
      }
      if (n16 == 0) {
#pragma unroll
        for (int r = 0; r < 4; ++r)
          pout[(t & 1) * 64 + wi * 16 + q * 4 + r] = vr[r];
      }
    }
    if (hasx) {  // stage x(t+1) in fragment order
      unsigned p0 = pk_enc(xv.x), p1 = pk_enc(xv.y), p2 = pk_enc(xv.z), p3 = pk_enc(xv.w);
      const int k0 = xf * 4;
      const int off = (k0 >> 3) * 256 + xb * 16 + (k0 & 7) * 2;
      *(unsigned*)(smem + IN_HI + off)     = (p0 >> 16) | (p1 & 0xFFFF0000u);
      *(unsigned*)(smem + IN_HI + off + 4) = (p2 >> 16) | (p3 & 0xFFFF0000u);
      *(unsigned*)(smem + IN_LO + off)     = (p0 & 0xFFFFu) | (p1 << 16);
      *(unsigned*)(smem + IN_LO + off + 4) = (p2 & 0xFFFFu) | (p3 << 16);
    }
  }
  __syncthreads();
  if (w == 0 && lane < 16) {  // final flush: h1(Sz-1) partials (parity Sz&1)
    const int par = Sz & 1;
    float s = pout[par * 64 + lane] + pout[par * 64 + 16 + lane]
            + pout[par * 64 + 32 + lane] + pout[par * 64 + 48 + lane];
    ghout[((size_t)(g * 8 + p) * Sz + (Sz - 1)) * 16 + lane] = s;
  }
}

extern "C" void kernel_launch(void* const* d_in, const int* in_sizes, int n_in,
                              void* d_out, int out_size, void* d_ws, size_t ws_size,
                              hipStream_t stream) {
  const float* xin   = (const float*)d_in[0];
  const float* W_in  = (const float*)d_in[1];
  const float* b_in  = (const float*)d_in[2];
  const float* W_ih0 = (const float*)d_in[3];
  const float* W_hh0 = (const float*)d_in[4];
  const float* b_ih0 = (const float*)d_in[5];
  const float* b_hh0 = (const float*)d_in[6];
  const float* W_ih1 = (const float*)d_in[7];
  const float* W_hh1 = (const float*)d_in[8];
  const float* b_ih1 = (const float*)d_in[9];
  const float* b_hh1 = (const float*)d_in[10];
  const float* W_out = (const float*)d_in[11];
  const float* b_out = (const float*)d_in[12];
  float* out = (float*)d_out;
  unsigned* ws = (unsigned*)d_ws;

  lstm_v5<<<32, 512, 0, stream>>>(xin, W_in, b_in, W_ih0, W_hh0, b_ih0, b_hh0,
                                  W_ih1, W_hh1, b_ih1, b_hh1, W_out, b_out, ws);
  out_reduce<<<(64 * Sz + 511) / 512, 512, 0, stream>>>(ws, b_out, out);
}